// Round 5
// baseline (395.865 us; speedup 1.0000x reference)
//
#include <hip/hip_runtime.h>

#define N_NODES 10000
#define N_EDGES 320000
#define MPAD 10112   // 79 * 128
#define NBIN 10048
#define CHUNK 2048
#define NCH 157      // ceil(E / CHUNK)

typedef unsigned short u16;
typedef short bf16x8 __attribute__((ext_vector_type(8)));
typedef float f32x4 __attribute__((ext_vector_type(4)));

__device__ __forceinline__ u16 f2b(float f) {
  unsigned u = __builtin_bit_cast(unsigned, f);
  unsigned r = u + 0x7fffu + ((u >> 16) & 1u);
  return (u16)(r >> 16);
}
__device__ __forceinline__ unsigned pack2(float a, float b) {
  return (unsigned)f2b(a) | ((unsigned)f2b(b) << 16);
}
__device__ __forceinline__ float blo(unsigned u) { return __builtin_bit_cast(float, u << 16); }
__device__ __forceinline__ float bhi(unsigned u) { return __builtin_bit_cast(float, u & 0xffff0000u); }

// ---------------------------------------------------------------- prep ------
__global__ void prep(
    const float* __restrict__ x,
    const float* __restrict__ w0, const float* __restrict__ w1, const float* __restrict__ w2,
    const float* __restrict__ fcw0, const float* __restrict__ injw0,
    const float* __restrict__ fcw1, const float* __restrict__ injw1,
    const float* __restrict__ outw,
    const float* __restrict__ fcb0, const float* __restrict__ injb0,
    const float* __restrict__ fcb1, const float* __restrict__ injb1,
    const float* __restrict__ alpha_p,
    u16* __restrict__ xb, u16* __restrict__ w0t, u16* __restrict__ w1t, u16* __restrict__ w2t,
    u16* __restrict__ wc1t, u16* __restrict__ wc2t, u16* __restrict__ owt,
    float* __restrict__ bias1, float* __restrict__ bias2)
{
  long i = (long)blockIdx.x * 256 + threadIdx.x;
  const float alpha = alpha_p[0];
  if (i < 640000L) {  // x -> bf16, 4 floats per thread
    float4 v = ((const float4*)x)[i];
    uint2 o;
    o.x = pack2(v.x, v.y);
    o.y = pack2(v.z, v.w);
    *(uint2*)(xb + 4 * i) = o;
    return;
  }
  i -= 640000L;
  if (i < 65536) { w0t[i] = f2b(w0[(i & 255) * 256 + (i >> 8)]); return; }
  i -= 65536;
  if (i < 65536) { w1t[i] = f2b(w1[(i & 255) * 256 + (i >> 8)]); return; }
  i -= 65536;
  if (i < 65536) { w2t[i] = f2b(w2[(i & 255) * 256 + (i >> 8)]); return; }
  i -= 65536;
  if (i < 262144) {  // Wcat1^T [512 n][512 k]: k<256 -> alpha*fc_w0 ; else inj_w0
    int n = (int)(i >> 9), k = (int)(i & 511);
    float v = (k < 256) ? alpha * fcw0[k * 512 + n] : injw0[(k - 256) * 512 + n];
    wc1t[i] = f2b(v); return;
  }
  i -= 262144;
  if (i < 393216) {  // Wcat2^T [512 n][768 k]: k<512 -> alpha*fc_w1 ; else inj_w1
    int n = (int)(i / 768), k = (int)(i % 768);
    float v = (k < 512) ? alpha * fcw1[k * 512 + n] : injw1[(k - 512) * 512 + n];
    wc2t[i] = f2b(v); return;
  }
  i -= 393216;
  if (i < 32768) {   // out_w^T [64 n][512 k]
    int n = (int)(i >> 9), k = (int)(i & 511);
    owt[i] = f2b(outw[k * 64 + n]); return;
  }
  i -= 32768;
  if (i < 512) { bias1[i] = alpha * fcb0[i] + injb0[i]; return; }
  i -= 512;
  if (i < 512) { bias2[i] = alpha * fcb1[i] + injb1[i]; return; }
}

// ----------------------------------------------------------- CSR build ------
// Deterministic chunked counting sort: no global read-modify-write anywhere
// (replay-safe). histR = per-chunk hist of dest r, histC = of source c.
__global__ __launch_bounds__(256) void edge_hist(const int* __restrict__ ei,
                                                 int* __restrict__ histR,
                                                 int* __restrict__ histC) {
  __shared__ int hr[NBIN], hc[NBIN];
  const int ch = blockIdx.x, t = threadIdx.x;
  for (int i = t; i < NBIN; i += 256) { hr[i] = 0; hc[i] = 0; }
  __syncthreads();
  const int e0 = ch * CHUNK;
#pragma unroll
  for (int j = 0; j < CHUNK; j += 256) {
    int e = e0 + j + t;
    if (e < N_EDGES) {
      atomicAdd(&hr[ei[e]], 1);
      atomicAdd(&hc[ei[N_EDGES + e]], 1);
    }
  }
  __syncthreads();
  for (int i = t; i < NBIN; i += 256) {
    histR[(size_t)ch * NBIN + i] = hr[i];
    histC[(size_t)ch * NBIN + i] = hc[i];
  }
}

// per-bin scan across chunks -> chunk offsets + per-bin totals + deg_inv
// (covers MPAD so GEMM pad rows read deg_inv = 1)
__global__ __launch_bounds__(256) void col_scan(const int* __restrict__ histR,
                                                const int* __restrict__ histC,
                                                int* __restrict__ chunkoff,
                                                int* __restrict__ cntR,
                                                float* __restrict__ deg_inv) {
  int r = blockIdx.x * 256 + threadIdx.x;
  if (r >= MPAD) return;
  if (r >= NBIN) { deg_inv[r] = 1.0f; return; }
  int run = 0, dg = 0;
#pragma unroll 4
  for (int ch = 0; ch < NCH; ++ch) {
    chunkoff[(size_t)ch * NBIN + r] = run;
    run += histR[(size_t)ch * NBIN + r];
    dg  += histC[(size_t)ch * NBIN + r];
  }
  cntR[r] = run;
  deg_inv[r] = 1.0f / (float)(dg > 1 ? dg : 1);
}

// single-block exclusive scan over cntR -> row_ptr[0..N_NODES]
__global__ __launch_bounds__(1024) void row_scan(const int* __restrict__ cntR,
                                                 int* __restrict__ row_ptr) {
  const int t = threadIdx.x;
  const int i0 = t * 10;
  int v[10];
  int s = 0;
#pragma unroll
  for (int i = 0; i < 10; ++i) {
    int id = i0 + i;
    v[i] = (id < NBIN) ? cntR[id] : 0;
    s += v[i];
  }
  int lane = t & 63, wid = t >> 6;
  int incl = s;
#pragma unroll
  for (int off = 1; off < 64; off <<= 1) {
    int y = __shfl_up(incl, off, 64);
    if (lane >= off) incl += y;
  }
  __shared__ int wsum[16], wexc[16];
  if (lane == 63) wsum[wid] = incl;
  __syncthreads();
  if (t == 0) {
    int run = 0;
#pragma unroll
    for (int i = 0; i < 16; ++i) { wexc[i] = run; run += wsum[i]; }
  }
  __syncthreads();
  int run = wexc[wid] + incl - s;
#pragma unroll
  for (int i = 0; i < 10; ++i) {
    int id = i0 + i;
    if (id <= N_NODES) row_ptr[id] = run;
    run += v[i];
  }
}

// placement: LDS cursor seeded from chunkoff (global state untouched)
__global__ __launch_bounds__(256) void place_edges(const int* __restrict__ ei,
                                                   const int* __restrict__ chunkoff,
                                                   const int* __restrict__ row_ptr,
                                                   int* __restrict__ csr) {
  __shared__ int cur[NBIN];
  const int ch = blockIdx.x, t = threadIdx.x;
  const int* co = chunkoff + (size_t)ch * NBIN;
  for (int i = t; i < NBIN; i += 256) cur[i] = co[i];
  __syncthreads();
  const int e0 = ch * CHUNK;
#pragma unroll
  for (int j = 0; j < CHUNK; j += 256) {
    int e = e0 + j + t;
    if (e < N_EDGES) {
      int r = ei[e];
      int c = ei[N_EDGES + e];
      int rank = atomicAdd(&cur[r], 1);   // LDS only; disjoint slots across chunks
      csr[row_ptr[r] + rank] = c;
    }
  }
}

// ------------------------------------------------------------- GEMM128 ------
// 128x128 tile, BK=64, 4 waves (2x2 quadrants of 64x64), each wave 4x4 MFMA
// 16x16x32 tiles. Halves A/B re-read traffic vs 64-tile (A re-read per column
// tile was the dominant hidden cost: FC2 was 247MB logical at 64-tiles).
template<int K, bool RELU, bool SCALE, bool F32OUT>
__global__ __launch_bounds__(256) void gemm128(
    const u16* __restrict__ A, int lda,
    const u16* __restrict__ Bt,
    const float* __restrict__ bias,
    const float* __restrict__ scale,
    u16* __restrict__ Cb, float* __restrict__ Cf, int ldc)
{
  __shared__ u16 As[128 * 72];   // +8 pad
  __shared__ u16 Bs[128 * 72];
  const int tid = threadIdx.x;
  const int m0 = blockIdx.x * 128;
  const int n0 = blockIdx.y * 128;
  const int wave = tid >> 6;
  const int lane = tid & 63;
  const int wr = (wave >> 1) * 64;
  const int wc = (wave & 1) * 64;
  const int lm = lane & 15;
  const int koff = (lane >> 4) * 8;

  const int srow = tid >> 1;          // 128 rows, 2 threads/row
  const int scol = (tid & 1) * 32;    // 32 u16 = 4 x int4 per thread
  const u16* Ag = A + (size_t)(m0 + srow) * lda + scol;
  const u16* Bg = Bt + (size_t)(n0 + srow) * K + scol;
  u16* Asw = &As[srow * 72 + scol];
  u16* Bsw = &Bs[srow * 72 + scol];

  f32x4 acc[4][4] = {};

  int4 pa[4], pb[4];
#pragma unroll
  for (int j = 0; j < 4; ++j) {
    pa[j] = *(const int4*)(Ag + 8 * j);
    pb[j] = *(const int4*)(Bg + 8 * j);
  }

#pragma unroll
  for (int kb = 0; kb < K; kb += 64) {
    __syncthreads();
#pragma unroll
    for (int j = 0; j < 4; ++j) {
      *(int4*)(Asw + 8 * j) = pa[j];
      *(int4*)(Bsw + 8 * j) = pb[j];
    }
    __syncthreads();
    if (kb + 64 < K) {
#pragma unroll
      for (int j = 0; j < 4; ++j) {
        pa[j] = *(const int4*)(Ag + kb + 64 + 8 * j);
        pb[j] = *(const int4*)(Bg + kb + 64 + 8 * j);
      }
    }
#pragma unroll
    for (int ks = 0; ks < 2; ++ks) {
      bf16x8 af[4], bf[4];
#pragma unroll
      for (int mi = 0; mi < 4; ++mi)
        af[mi] = *(const bf16x8*)&As[(wr + mi * 16 + lm) * 72 + ks * 32 + koff];
#pragma unroll
      for (int ni = 0; ni < 4; ++ni)
        bf[ni] = *(const bf16x8*)&Bs[(wc + ni * 16 + lm) * 72 + ks * 32 + koff];
#pragma unroll
      for (int mi = 0; mi < 4; ++mi)
#pragma unroll
        for (int ni = 0; ni < 4; ++ni)
          acc[mi][ni] = __builtin_amdgcn_mfma_f32_16x16x32_bf16(af[mi], bf[ni], acc[mi][ni], 0, 0, 0);
    }
  }

  const int q4 = (lane >> 4) * 4;
#pragma unroll
  for (int mi = 0; mi < 4; ++mi) {
#pragma unroll
    for (int ni = 0; ni < 4; ++ni) {
      const int gc = n0 + wc + ni * 16 + lm;
      const float bv = bias[gc];
#pragma unroll
      for (int r = 0; r < 4; ++r) {
        const int gr = m0 + wr + mi * 16 + q4 + r;
        float v = acc[mi][ni][r] + bv;
        if (RELU) v = fmaxf(v, 0.f);
        if (SCALE) v *= scale[gr];
        if (F32OUT) {
          if (gr < N_NODES) Cf[(size_t)gr * ldc + gc] = v;
        } else {
          Cb[(size_t)gr * ldc + gc] = f2b(v);
        }
      }
    }
  }
}

// -------------------------------------------------------------- GEMM64 ------
// kept for the N=64 output GEMM only
template<int K, bool RELU, bool SCALE, bool F32OUT>
__global__ __launch_bounds__(256) void gemm64(
    const u16* __restrict__ A, int lda,
    const u16* __restrict__ Bt,
    const float* __restrict__ bias,
    const float* __restrict__ scale,
    u16* __restrict__ Cb, float* __restrict__ Cf, int ldc)
{
  __shared__ u16 As[64 * 72];
  __shared__ u16 Bs[64 * 72];
  const int tid = threadIdx.x;
  const int m0 = blockIdx.x * 64;
  const int n0 = blockIdx.y * 64;
  const int wave = tid >> 6;
  const int lane = tid & 63;
  const int wr = (wave >> 1) * 32;
  const int wc = (wave & 1) * 32;
  const int lm = lane & 15;
  const int koff = (lane >> 4) * 8;

  const int srow = tid >> 2;
  const int scol = (tid & 3) * 16;
  const u16* Ag = A + (size_t)(m0 + srow) * lda + scol;
  const u16* Bg = Bt + (size_t)(n0 + srow) * K + scol;
  u16* Asw = &As[srow * 72 + scol];
  u16* Bsw = &Bs[srow * 72 + scol];

  f32x4 acc[2][2] = {};

  int4 a0 = *(const int4*)(Ag);
  int4 a1 = *(const int4*)(Ag + 8);
  int4 b0 = *(const int4*)(Bg);
  int4 b1 = *(const int4*)(Bg + 8);

#pragma unroll
  for (int kb = 0; kb < K; kb += 64) {
    __syncthreads();
    *(int4*)Asw = a0; *(int4*)(Asw + 8) = a1;
    *(int4*)Bsw = b0; *(int4*)(Bsw + 8) = b1;
    __syncthreads();
    if (kb + 64 < K) {
      a0 = *(const int4*)(Ag + kb + 64);
      a1 = *(const int4*)(Ag + kb + 72);
      b0 = *(const int4*)(Bg + kb + 64);
      b1 = *(const int4*)(Bg + kb + 72);
    }
#pragma unroll
    for (int ks = 0; ks < 2; ++ks) {
      bf16x8 af0 = *(const bf16x8*)&As[(wr + lm) * 72 + ks * 32 + koff];
      bf16x8 af1 = *(const bf16x8*)&As[(wr + 16 + lm) * 72 + ks * 32 + koff];
      bf16x8 bf0 = *(const bf16x8*)&Bs[(wc + lm) * 72 + ks * 32 + koff];
      bf16x8 bf1 = *(const bf16x8*)&Bs[(wc + 16 + lm) * 72 + ks * 32 + koff];
      acc[0][0] = __builtin_amdgcn_mfma_f32_16x16x32_bf16(af0, bf0, acc[0][0], 0, 0, 0);
      acc[0][1] = __builtin_amdgcn_mfma_f32_16x16x32_bf16(af0, bf1, acc[0][1], 0, 0, 0);
      acc[1][0] = __builtin_amdgcn_mfma_f32_16x16x32_bf16(af1, bf0, acc[1][0], 0, 0, 0);
      acc[1][1] = __builtin_amdgcn_mfma_f32_16x16x32_bf16(af1, bf1, acc[1][1], 0, 0, 0);
    }
  }

  const int q4 = (lane >> 4) * 4;
#pragma unroll
  for (int i = 0; i < 2; ++i) {
#pragma unroll
    for (int j = 0; j < 2; ++j) {
      const int gc = n0 + wc + j * 16 + lm;
      const float bv = bias[gc];
#pragma unroll
      for (int r = 0; r < 4; ++r) {
        const int gr = m0 + wr + i * 16 + q4 + r;
        float v = acc[i][j][r] + bv;
        if (RELU) v = fmaxf(v, 0.f);
        if (SCALE) v *= scale[gr];
        if (F32OUT) {
          if (gr < N_NODES) Cf[(size_t)gr * ldc + gc] = v;
        } else {
          Cb[(size_t)gr * ldc + gc] = f2b(v);
        }
      }
    }
  }
}

// ----------------------------------------------------------- aggregate ------
// One WAVE per node; PAIRED gather: half-wave (32 lanes) per neighbor,
// dwordx4 (8 bf16)/lane -> 2 neighbors per step, unroll 4 -> 8 neighbors /
// 16B-per-lane loads in flight. Cross-half __shfl reduction at the end.
__global__ __launch_bounds__(256) void aggregate(
    const u16* __restrict__ tmp, const int* __restrict__ row_ptr,
    const int* __restrict__ csr, u16* __restrict__ out0,
    u16* __restrict__ A1, u16* __restrict__ A2, int mode)
{
  const int wv = threadIdx.x >> 6;
  const int lane = threadIdx.x & 63;
  const int r = blockIdx.x * 4 + wv;          // grid = 2500 -> r in [0,10000)
  const int half = lane >> 5;                 // which neighbor of the pair
  const int q = lane & 31;
  const int beg = row_ptr[r], end = row_ptr[r + 1];
  const size_t feat = (size_t)q * 16;         // byte offset into 512B row
  const char* tb = (const char*)tmp;

  float s0 = 0.f, s1 = 0.f, s2 = 0.f, s3 = 0.f, s4 = 0.f, s5 = 0.f, s6 = 0.f, s7 = 0.f;
  int i = beg;
  for (; i + 8 <= end; i += 8) {
    uint4 v[4];
#pragma unroll
    for (int j = 0; j < 4; ++j)
      v[j] = *(const uint4*)(tb + (size_t)csr[i + 2 * j + half] * 512 + feat);
#pragma unroll
    for (int j = 0; j < 4; ++j) {
      s0 += blo(v[j].x); s1 += bhi(v[j].x); s2 += blo(v[j].y); s3 += bhi(v[j].y);
      s4 += blo(v[j].z); s5 += bhi(v[j].z); s6 += blo(v[j].w); s7 += bhi(v[j].w);
    }
  }
  for (; i < end; i += 2) {
    int id = i + half;
    if (id < end) {
      uint4 v = *(const uint4*)(tb + (size_t)csr[id] * 512 + feat);
      s0 += blo(v.x); s1 += bhi(v.x); s2 += blo(v.y); s3 += bhi(v.y);
      s4 += blo(v.z); s5 += bhi(v.z); s6 += blo(v.w); s7 += bhi(v.w);
    }
  }
  // cross-half reduce: lane q and q+32 hold the same feature range
  const int src = lane ^ 32;
  s0 += __shfl(s0, src, 64); s1 += __shfl(s1, src, 64);
  s2 += __shfl(s2, src, 64); s3 += __shfl(s3, src, 64);
  s4 += __shfl(s4, src, 64); s5 += __shfl(s5, src, 64);
  s6 += __shfl(s6, src, 64); s7 += __shfl(s7, src, 64);

  if (half == 0) {
    uint4 pv;
    pv.x = pack2(s0, s1); pv.y = pack2(s2, s3);
    pv.z = pack2(s4, s5); pv.w = pack2(s6, s7);
    if (mode == 0) {
      *(uint4*)((char*)out0 + (size_t)r * 512 + feat) = pv;
    } else {
      uint4 pr;
      pr.x = pack2(fmaxf(s0, 0.f), fmaxf(s1, 0.f));
      pr.y = pack2(fmaxf(s2, 0.f), fmaxf(s3, 0.f));
      pr.z = pack2(fmaxf(s4, 0.f), fmaxf(s5, 0.f));
      pr.w = pack2(fmaxf(s6, 0.f), fmaxf(s7, 0.f));
      *(uint4*)((char*)A1 + (size_t)r * 1024 + feat) = pr;          // relu(h3)
      *(uint4*)((char*)A1 + (size_t)r * 1024 + 512 + feat) = pv;    // h3
      *(uint4*)((char*)A2 + (size_t)r * 1536 + 1024 + feat) = pv;   // h3 tail
    }
  }
}

// -------------------------------------------------------------- launch ------
extern "C" void kernel_launch(void* const* d_in, const int* in_sizes, int n_in,
                              void* d_out, int out_size, void* d_ws, size_t ws_size,
                              hipStream_t stream) {
  const float* x      = (const float*)d_in[0];
  const int*   ei     = (const int*)d_in[1];   // int inputs arrive as int32
  const float* mp_w0  = (const float*)d_in[2];
  const float* mp_b0  = (const float*)d_in[3];
  const float* mp_w1  = (const float*)d_in[4];
  const float* mp_b1  = (const float*)d_in[5];
  const float* mp_w2  = (const float*)d_in[6];
  const float* mp_b2  = (const float*)d_in[7];
  const float* fc_w0  = (const float*)d_in[8];
  const float* fc_b0  = (const float*)d_in[9];
  const float* fc_w1  = (const float*)d_in[10];
  const float* fc_b1  = (const float*)d_in[11];
  const float* inj_w0 = (const float*)d_in[12];
  const float* inj_b0 = (const float*)d_in[13];
  const float* inj_w1 = (const float*)d_in[14];
  const float* inj_b1 = (const float*)d_in[15];
  const float* alpha  = (const float*)d_in[16];
  const float* out_w  = (const float*)d_in[17];
  const float* out_b  = (const float*)d_in[18];
  float* out = (float*)d_out;

  char* p = (char*)d_ws;
  auto carve = [&](size_t bytes) -> void* {
    void* r = (void*)p;
    p += (bytes + 255) & ~(size_t)255;
    return r;
  };
  int*   histR    = (int*)carve((size_t)NCH * NBIN * 4);
  int*   histC    = (int*)carve((size_t)NCH * NBIN * 4);
  int*   chunkoff = (int*)carve((size_t)NCH * NBIN * 4);
  int*   cntR     = (int*)carve(NBIN * 4);
  int*   row_ptr  = (int*)carve((N_NODES + 1) * 4);
  int*   csr      = (int*)carve((size_t)N_EDGES * 4);
  float* deg_inv  = (float*)carve(MPAD * 4);
  float* bias1    = (float*)carve(512 * 4);
  float* bias2    = (float*)carve(512 * 4);
  u16* xb   = (u16*)carve((size_t)MPAD * 256 * 2);
  u16* w0t  = (u16*)carve(65536 * 2);
  u16* w1t  = (u16*)carve(65536 * 2);
  u16* w2t  = (u16*)carve(65536 * 2);
  u16* wc1t = (u16*)carve(262144 * 2);
  u16* wc2t = (u16*)carve(393216 * 2);
  u16* owt  = (u16*)carve(32768 * 2);
  u16* tmp  = (u16*)carve((size_t)MPAD * 256 * 2);
  u16* h    = (u16*)carve((size_t)MPAD * 256 * 2);
  u16* A1   = (u16*)carve((size_t)MPAD * 512 * 2);
  u16* A2   = (u16*)carve((size_t)MPAD * 768 * 2);
  u16* C2   = (u16*)carve((size_t)MPAD * 512 * 2);

  prep<<<5960, 256, 0, stream>>>(x, mp_w0, mp_w1, mp_w2, fc_w0, inj_w0, fc_w1, inj_w1,
                                 out_w, fc_b0, inj_b0, fc_b1, inj_b1, alpha,
                                 xb, w0t, w1t, w2t, wc1t, wc2t, owt, bias1, bias2);
  edge_hist<<<NCH, 256, 0, stream>>>(ei, histR, histC);
  col_scan<<<(MPAD + 255) / 256, 256, 0, stream>>>(histR, histC, chunkoff, cntR, deg_inv);
  row_scan<<<1, 1024, 0, stream>>>(cntR, row_ptr);
  place_edges<<<NCH, 256, 0, stream>>>(ei, chunkoff, row_ptr, csr);

  dim3 gmp(MPAD / 128, 2), gfc(MPAD / 128, 4), go(MPAD / 64, 1);
  // MP layer 1..3: tmp = relu(h @ W + b) * deg_inv ; h' = CSR-aggregate(tmp)
  gemm128<256, true, true, false><<<gmp, 256, 0, stream>>>(xb, 256, w0t, mp_b0, deg_inv, tmp, nullptr, 256);
  aggregate<<<2500, 256, 0, stream>>>(tmp, row_ptr, csr, h, nullptr, nullptr, 0);
  gemm128<256, true, true, false><<<gmp, 256, 0, stream>>>(h, 256, w1t, mp_b1, deg_inv, tmp, nullptr, 256);
  aggregate<<<2500, 256, 0, stream>>>(tmp, row_ptr, csr, h, nullptr, nullptr, 0);
  gemm128<256, true, true, false><<<gmp, 256, 0, stream>>>(h, 256, w2t, mp_b2, deg_inv, tmp, nullptr, 256);
  aggregate<<<2500, 256, 0, stream>>>(tmp, row_ptr, csr, nullptr, A1, A2, 1);
  // FC1 (+inj0 fused, K=512) -> relu -> A2[:, 0:512]
  gemm128<512, true, false, false><<<gfc, 256, 0, stream>>>(A1, 512, wc1t, bias1, nullptr, A2, nullptr, 768);
  // FC2 (+inj1 fused, K=768) -> C2
  gemm128<768, false, false, false><<<gfc, 256, 0, stream>>>(A2, 768, wc2t, bias2, nullptr, C2, nullptr, 512);
  // out = C2 @ out_w + out_b  (fp32 store, row-guarded)
  gemm64<512, false, false, true><<<go, 256, 0, stream>>>(C2, 512, owt, out_b, nullptr, nullptr, out, 64);
}

// Round 7
// 267.914 us; speedup vs baseline: 1.4776x; 1.4776x over previous
//
#include <hip/hip_runtime.h>

#define N_NODES 10000
#define N_EDGES 320000
#define MPAD 10112   // 158 * 64
#define NBIN 10048
#define CHUNK 2048
#define NCH 157      // ceil(E / CHUNK)

typedef unsigned short u16;
typedef short bf16x8 __attribute__((ext_vector_type(8)));
typedef float f32x4 __attribute__((ext_vector_type(4)));

__device__ __forceinline__ u16 f2b(float f) {
  unsigned u = __builtin_bit_cast(unsigned, f);
  unsigned r = u + 0x7fffu + ((u >> 16) & 1u);
  return (u16)(r >> 16);
}
__device__ __forceinline__ unsigned pack2(float a, float b) {
  return (unsigned)f2b(a) | ((unsigned)f2b(b) << 16);
}
__device__ __forceinline__ float blo(unsigned u) { return __builtin_bit_cast(float, u << 16); }
__device__ __forceinline__ float bhi(unsigned u) { return __builtin_bit_cast(float, u & 0xffff0000u); }

// ---------------------------------------------------------------- prep ------
__global__ void prep(
    const float* __restrict__ x,
    const float* __restrict__ w0, const float* __restrict__ w1, const float* __restrict__ w2,
    const float* __restrict__ fcw0, const float* __restrict__ injw0,
    const float* __restrict__ fcw1, const float* __restrict__ injw1,
    const float* __restrict__ outw,
    const float* __restrict__ fcb0, const float* __restrict__ injb0,
    const float* __restrict__ fcb1, const float* __restrict__ injb1,
    const float* __restrict__ alpha_p,
    u16* __restrict__ xb, u16* __restrict__ w0t, u16* __restrict__ w1t, u16* __restrict__ w2t,
    u16* __restrict__ wc1t, u16* __restrict__ wc2t, u16* __restrict__ owt,
    float* __restrict__ bias1, float* __restrict__ bias2)
{
  long i = (long)blockIdx.x * 256 + threadIdx.x;
  const float alpha = alpha_p[0];
  if (i < 640000L) {  // x -> bf16, 4 floats per thread
    float4 v = ((const float4*)x)[i];
    uint2 o;
    o.x = pack2(v.x, v.y);
    o.y = pack2(v.z, v.w);
    *(uint2*)(xb + 4 * i) = o;
    return;
  }
  i -= 640000L;
  if (i < 65536) { w0t[i] = f2b(w0[(i & 255) * 256 + (i >> 8)]); return; }
  i -= 65536;
  if (i < 65536) { w1t[i] = f2b(w1[(i & 255) * 256 + (i >> 8)]); return; }
  i -= 65536;
  if (i < 65536) { w2t[i] = f2b(w2[(i & 255) * 256 + (i >> 8)]); return; }
  i -= 65536;
  if (i < 262144) {  // Wcat1^T [512 n][512 k]: k<256 -> alpha*fc_w0 ; else inj_w0
    int n = (int)(i >> 9), k = (int)(i & 511);
    float v = (k < 256) ? alpha * fcw0[k * 512 + n] : injw0[(k - 256) * 512 + n];
    wc1t[i] = f2b(v); return;
  }
  i -= 262144;
  if (i < 393216) {  // Wcat2^T [512 n][768 k]: k<512 -> alpha*fc_w1 ; else inj_w1
    int n = (int)(i / 768), k = (int)(i % 768);
    float v = (k < 512) ? alpha * fcw1[k * 512 + n] : injw1[(k - 512) * 512 + n];
    wc2t[i] = f2b(v); return;
  }
  i -= 393216;
  if (i < 32768) {   // out_w^T [64 n][512 k]
    int n = (int)(i >> 9), k = (int)(i & 511);
    owt[i] = f2b(outw[k * 64 + n]); return;
  }
  i -= 32768;
  if (i < 512) { bias1[i] = alpha * fcb0[i] + injb0[i]; return; }
  i -= 512;
  if (i < 512) { bias2[i] = alpha * fcb1[i] + injb1[i]; return; }
}

// ----------------------------------------------------------- CSR build ------
// Deterministic chunked counting sort (replay-safe, no global RMW).
__global__ __launch_bounds__(256) void edge_hist(const int* __restrict__ ei,
                                                 int* __restrict__ histR,
                                                 int* __restrict__ histC) {
  __shared__ int hr[NBIN], hc[NBIN];
  const int ch = blockIdx.x, t = threadIdx.x;
  for (int i = t; i < NBIN; i += 256) { hr[i] = 0; hc[i] = 0; }
  __syncthreads();
  const int e0 = ch * CHUNK;
#pragma unroll
  for (int j = 0; j < CHUNK; j += 256) {
    int e = e0 + j + t;
    if (e < N_EDGES) {
      atomicAdd(&hr[ei[e]], 1);
      atomicAdd(&hc[ei[N_EDGES + e]], 1);
    }
  }
  __syncthreads();
  for (int i = t; i < NBIN; i += 256) {
    histR[(size_t)ch * NBIN + i] = hr[i];
    histC[(size_t)ch * NBIN + i] = hc[i];
  }
}

__global__ __launch_bounds__(256) void col_scan(const int* __restrict__ histR,
                                                const int* __restrict__ histC,
                                                int* __restrict__ chunkoff,
                                                int* __restrict__ cntR,
                                                float* __restrict__ deg_inv) {
  int r = blockIdx.x * 256 + threadIdx.x;
  if (r >= MPAD) return;
  if (r >= NBIN) { deg_inv[r] = 1.0f; return; }
  int run = 0, dg = 0;
#pragma unroll 4
  for (int ch = 0; ch < NCH; ++ch) {
    chunkoff[(size_t)ch * NBIN + r] = run;
    run += histR[(size_t)ch * NBIN + r];
    dg  += histC[(size_t)ch * NBIN + r];
  }
  cntR[r] = run;
  deg_inv[r] = 1.0f / (float)(dg > 1 ? dg : 1);
}

__global__ __launch_bounds__(1024) void row_scan(const int* __restrict__ cntR,
                                                 int* __restrict__ row_ptr) {
  const int t = threadIdx.x;
  const int i0 = t * 10;
  int v[10];
  int s = 0;
#pragma unroll
  for (int i = 0; i < 10; ++i) {
    int id = i0 + i;
    v[i] = (id < NBIN) ? cntR[id] : 0;
    s += v[i];
  }
  int lane = t & 63, wid = t >> 6;
  int incl = s;
#pragma unroll
  for (int off = 1; off < 64; off <<= 1) {
    int y = __shfl_up(incl, off, 64);
    if (lane >= off) incl += y;
  }
  __shared__ int wsum[16], wexc[16];
  if (lane == 63) wsum[wid] = incl;
  __syncthreads();
  if (t == 0) {
    int run = 0;
#pragma unroll
    for (int i = 0; i < 16; ++i) { wexc[i] = run; run += wsum[i]; }
  }
  __syncthreads();
  int run = wexc[wid] + incl - s;
#pragma unroll
  for (int i = 0; i < 10; ++i) {
    int id = i0 + i;
    if (id <= N_NODES) row_ptr[id] = run;
    run += v[i];
  }
}

__global__ __launch_bounds__(256) void place_edges(const int* __restrict__ ei,
                                                   const int* __restrict__ chunkoff,
                                                   const int* __restrict__ row_ptr,
                                                   int* __restrict__ csr) {
  __shared__ int cur[NBIN];
  const int ch = blockIdx.x, t = threadIdx.x;
  const int* co = chunkoff + (size_t)ch * NBIN;
  for (int i = t; i < NBIN; i += 256) cur[i] = co[i];
  __syncthreads();
  const int e0 = ch * CHUNK;
#pragma unroll
  for (int j = 0; j < CHUNK; j += 256) {
    int e = e0 + j + t;
    if (e < N_EDGES) {
      int r = ei[e];
      int c = ei[N_EDGES + e];
      int rank = atomicAdd(&cur[r], 1);   // LDS only; disjoint slots across chunks
      csr[row_ptr[r] + rank] = c;
    }
  }
}

// ---------------------------------------------------------------- GEMM ------
// 64x64 tile, TWO waves per block (128 threads): each wave computes 32x64
// (2x4 MFMA 16x16x32 frags). R5 post-mortem: 316-block gemm128 grid = 1
// block/CU -> 10% occupancy -> 71us latency-bound dispatches. 128-thr blocks
// give 632-1264 blocks and ~8 resident blocks/CU.
// R6 post-mortem: staging must write TWO int4 per row per thread (16 u16);
// R6 wrote one -> half of LDS uninitialized -> absmax 3e19.
template<int K, bool RELU, bool SCALE, bool F32OUT>
__global__ __launch_bounds__(128) void gemm64(
    const u16* __restrict__ A, int lda,
    const u16* __restrict__ Bt,
    const float* __restrict__ bias,
    const float* __restrict__ scale,
    u16* __restrict__ Cb, float* __restrict__ Cf, int ldc)
{
  __shared__ u16 As[64 * 72];   // +8 pad: benign bank spread
  __shared__ u16 Bs[64 * 72];
  const int tid = threadIdx.x;
  const int m0 = blockIdx.x * 64;
  const int n0 = blockIdx.y * 64;
  const int wave = tid >> 6;          // 0..1
  const int lane = tid & 63;
  const int wr = wave * 32;           // wave's 32-row strip
  const int lm = lane & 15;
  const int koff = (lane >> 4) * 8;

  const int srow = tid >> 2;          // 0..31 (stages rows srow and srow+32)
  const int scol = (tid & 3) * 16;    // 16 u16 per row = 2 int4
  const u16* Ag0 = A + (size_t)(m0 + srow) * lda + scol;
  const u16* Ag1 = A + (size_t)(m0 + srow + 32) * lda + scol;
  const u16* Bg0 = Bt + (size_t)(n0 + srow) * K + scol;
  const u16* Bg1 = Bt + (size_t)(n0 + srow + 32) * K + scol;
  u16* Asw0 = &As[srow * 72 + scol];
  u16* Asw1 = &As[(srow + 32) * 72 + scol];
  u16* Bsw0 = &Bs[srow * 72 + scol];
  u16* Bsw1 = &Bs[(srow + 32) * 72 + scol];

  f32x4 acc[2][4] = {};

  // prefetch tile 0: 2 int4 per row, 2 rows, A and B
  int4 pa0 = *(const int4*)(Ag0),     pa1 = *(const int4*)(Ag0 + 8);
  int4 pa2 = *(const int4*)(Ag1),     pa3 = *(const int4*)(Ag1 + 8);
  int4 pb0 = *(const int4*)(Bg0),     pb1 = *(const int4*)(Bg0 + 8);
  int4 pb2 = *(const int4*)(Bg1),     pb3 = *(const int4*)(Bg1 + 8);

#pragma unroll
  for (int kb = 0; kb < K; kb += 64) {
    __syncthreads();
    *(int4*)Asw0 = pa0; *(int4*)(Asw0 + 8) = pa1;
    *(int4*)Asw1 = pa2; *(int4*)(Asw1 + 8) = pa3;
    *(int4*)Bsw0 = pb0; *(int4*)(Bsw0 + 8) = pb1;
    *(int4*)Bsw1 = pb2; *(int4*)(Bsw1 + 8) = pb3;
    __syncthreads();
    if (kb + 64 < K) {  // prefetch next tile; latency hidden under MFMAs
      pa0 = *(const int4*)(Ag0 + kb + 64); pa1 = *(const int4*)(Ag0 + kb + 72);
      pa2 = *(const int4*)(Ag1 + kb + 64); pa3 = *(const int4*)(Ag1 + kb + 72);
      pb0 = *(const int4*)(Bg0 + kb + 64); pb1 = *(const int4*)(Bg0 + kb + 72);
      pb2 = *(const int4*)(Bg1 + kb + 64); pb3 = *(const int4*)(Bg1 + kb + 72);
    }
#pragma unroll
    for (int ks = 0; ks < 2; ++ks) {
      bf16x8 af[2], bf[4];
#pragma unroll
      for (int mi = 0; mi < 2; ++mi)
        af[mi] = *(const bf16x8*)&As[(wr + mi * 16 + lm) * 72 + ks * 32 + koff];
#pragma unroll
      for (int ni = 0; ni < 4; ++ni)
        bf[ni] = *(const bf16x8*)&Bs[(ni * 16 + lm) * 72 + ks * 32 + koff];
#pragma unroll
      for (int mi = 0; mi < 2; ++mi)
#pragma unroll
        for (int ni = 0; ni < 4; ++ni)
          acc[mi][ni] = __builtin_amdgcn_mfma_f32_16x16x32_bf16(af[mi], bf[ni], acc[mi][ni], 0, 0, 0);
    }
  }

  const int q4 = (lane >> 4) * 4;
#pragma unroll
  for (int mi = 0; mi < 2; ++mi) {
#pragma unroll
    for (int ni = 0; ni < 4; ++ni) {
      const int gc = n0 + ni * 16 + lm;
      const float bv = bias[gc];
#pragma unroll
      for (int r = 0; r < 4; ++r) {
        const int gr = m0 + wr + mi * 16 + q4 + r;
        float v = acc[mi][ni][r] + bv;
        if (RELU) v = fmaxf(v, 0.f);
        if (SCALE) v *= scale[gr];
        if (F32OUT) {
          if (gr < N_NODES) Cf[(size_t)gr * ldc + gc] = v;
        } else {
          Cb[(size_t)gr * ldc + gc] = f2b(v);
        }
      }
    }
  }
}

// ----------------------------------------------------------- aggregate ------
// One WAVE per node; PAIRED gather: half-wave (32 lanes) per neighbor,
// dwordx4 (8 bf16)/lane -> 2 neighbors per step, unroll 4 -> 8 neighbors
// in flight. Cross-half __shfl reduction at the end.
__global__ __launch_bounds__(256) void aggregate(
    const u16* __restrict__ tmp, const int* __restrict__ row_ptr,
    const int* __restrict__ csr, u16* __restrict__ out0,
    u16* __restrict__ A1, u16* __restrict__ A2, int mode)
{
  const int wv = threadIdx.x >> 6;
  const int lane = threadIdx.x & 63;
  const int r = blockIdx.x * 4 + wv;          // grid = 2500 -> r in [0,10000)
  const int half = lane >> 5;                 // which neighbor of the pair
  const int q = lane & 31;
  const int beg = row_ptr[r], end = row_ptr[r + 1];
  const size_t feat = (size_t)q * 16;         // byte offset into 512B row
  const char* tb = (const char*)tmp;

  float s0 = 0.f, s1 = 0.f, s2 = 0.f, s3 = 0.f, s4 = 0.f, s5 = 0.f, s6 = 0.f, s7 = 0.f;
  int i = beg;
  for (; i + 8 <= end; i += 8) {
    uint4 v[4];
#pragma unroll
    for (int j = 0; j < 4; ++j)
      v[j] = *(const uint4*)(tb + (size_t)csr[i + 2 * j + half] * 512 + feat);
#pragma unroll
    for (int j = 0; j < 4; ++j) {
      s0 += blo(v[j].x); s1 += bhi(v[j].x); s2 += blo(v[j].y); s3 += bhi(v[j].y);
      s4 += blo(v[j].z); s5 += bhi(v[j].z); s6 += blo(v[j].w); s7 += bhi(v[j].w);
    }
  }
  for (; i < end; i += 2) {
    int id = i + half;
    if (id < end) {
      uint4 v = *(const uint4*)(tb + (size_t)csr[id] * 512 + feat);
      s0 += blo(v.x); s1 += bhi(v.x); s2 += blo(v.y); s3 += bhi(v.y);
      s4 += blo(v.z); s5 += bhi(v.z); s6 += blo(v.w); s7 += bhi(v.w);
    }
  }
  const int src = lane ^ 32;
  s0 += __shfl(s0, src, 64); s1 += __shfl(s1, src, 64);
  s2 += __shfl(s2, src, 64); s3 += __shfl(s3, src, 64);
  s4 += __shfl(s4, src, 64); s5 += __shfl(s5, src, 64);
  s6 += __shfl(s6, src, 64); s7 += __shfl(s7, src, 64);

  if (half == 0) {
    uint4 pv;
    pv.x = pack2(s0, s1); pv.y = pack2(s2, s3);
    pv.z = pack2(s4, s5); pv.w = pack2(s6, s7);
    if (mode == 0) {
      *(uint4*)((char*)out0 + (size_t)r * 512 + feat) = pv;
    } else {
      uint4 pr;
      pr.x = pack2(fmaxf(s0, 0.f), fmaxf(s1, 0.f));
      pr.y = pack2(fmaxf(s2, 0.f), fmaxf(s3, 0.f));
      pr.z = pack2(fmaxf(s4, 0.f), fmaxf(s5, 0.f));
      pr.w = pack2(fmaxf(s6, 0.f), fmaxf(s7, 0.f));
      *(uint4*)((char*)A1 + (size_t)r * 1024 + feat) = pr;          // relu(h3)
      *(uint4*)((char*)A1 + (size_t)r * 1024 + 512 + feat) = pv;    // h3
      *(uint4*)((char*)A2 + (size_t)r * 1536 + 1024 + feat) = pv;   // h3 tail
    }
  }
}

// -------------------------------------------------------------- launch ------
extern "C" void kernel_launch(void* const* d_in, const int* in_sizes, int n_in,
                              void* d_out, int out_size, void* d_ws, size_t ws_size,
                              hipStream_t stream) {
  const float* x      = (const float*)d_in[0];
  const int*   ei     = (const int*)d_in[1];   // int inputs arrive as int32
  const float* mp_w0  = (const float*)d_in[2];
  const float* mp_b0  = (const float*)d_in[3];
  const float* mp_w1  = (const float*)d_in[4];
  const float* mp_b1  = (const float*)d_in[5];
  const float* mp_w2  = (const float*)d_in[6];
  const float* mp_b2  = (const float*)d_in[7];
  const float* fc_w0  = (const float*)d_in[8];
  const float* fc_b0  = (const float*)d_in[9];
  const float* fc_w1  = (const float*)d_in[10];
  const float* fc_b1  = (const float*)d_in[11];
  const float* inj_w0 = (const float*)d_in[12];
  const float* inj_b0 = (const float*)d_in[13];
  const float* inj_w1 = (const float*)d_in[14];
  const float* inj_b1 = (const float*)d_in[15];
  const float* alpha  = (const float*)d_in[16];
  const float* out_w  = (const float*)d_in[17];
  const float* out_b  = (const float*)d_in[18];
  float* out = (float*)d_out;

  char* p = (char*)d_ws;
  auto carve = [&](size_t bytes) -> void* {
    void* r = (void*)p;
    p += (bytes + 255) & ~(size_t)255;
    return r;
  };
  int*   histR    = (int*)carve((size_t)NCH * NBIN * 4);
  int*   histC    = (int*)carve((size_t)NCH * NBIN * 4);
  int*   chunkoff = (int*)carve((size_t)NCH * NBIN * 4);
  int*   cntR     = (int*)carve(NBIN * 4);
  int*   row_ptr  = (int*)carve((N_NODES + 1) * 4);
  int*   csr      = (int*)carve((size_t)N_EDGES * 4);
  float* deg_inv  = (float*)carve(MPAD * 4);
  float* bias1    = (float*)carve(512 * 4);
  float* bias2    = (float*)carve(512 * 4);
  u16* xb   = (u16*)carve((size_t)MPAD * 256 * 2);
  u16* w0t  = (u16*)carve(65536 * 2);
  u16* w1t  = (u16*)carve(65536 * 2);
  u16* w2t  = (u16*)carve(65536 * 2);
  u16* wc1t = (u16*)carve(262144 * 2);
  u16* wc2t = (u16*)carve(393216 * 2);
  u16* owt  = (u16*)carve(32768 * 2);
  u16* tmp  = (u16*)carve((size_t)MPAD * 256 * 2);
  u16* h    = (u16*)carve((size_t)MPAD * 256 * 2);
  u16* A1   = (u16*)carve((size_t)MPAD * 512 * 2);
  u16* A2   = (u16*)carve((size_t)MPAD * 768 * 2);
  u16* C2   = (u16*)carve((size_t)MPAD * 512 * 2);

  prep<<<5960, 256, 0, stream>>>(x, mp_w0, mp_w1, mp_w2, fc_w0, inj_w0, fc_w1, inj_w1,
                                 out_w, fc_b0, inj_b0, fc_b1, inj_b1, alpha,
                                 xb, w0t, w1t, w2t, wc1t, wc2t, owt, bias1, bias2);
  edge_hist<<<NCH, 256, 0, stream>>>(ei, histR, histC);
  col_scan<<<(MPAD + 255) / 256, 256, 0, stream>>>(histR, histC, chunkoff, cntR, deg_inv);
  row_scan<<<1, 1024, 0, stream>>>(cntR, row_ptr);
  place_edges<<<NCH, 256, 0, stream>>>(ei, chunkoff, row_ptr, csr);

  dim3 gmp(MPAD / 64, 4), gfc(MPAD / 64, 8), go(MPAD / 64, 1);
  // MP layer 1..3: tmp = relu(h @ W + b) * deg_inv ; h' = CSR-aggregate(tmp)
  gemm64<256, true, true, false><<<gmp, 128, 0, stream>>>(xb, 256, w0t, mp_b0, deg_inv, tmp, nullptr, 256);
  aggregate<<<2500, 256, 0, stream>>>(tmp, row_ptr, csr, h, nullptr, nullptr, 0);
  gemm64<256, true, true, false><<<gmp, 128, 0, stream>>>(h, 256, w1t, mp_b1, deg_inv, tmp, nullptr, 256);
  aggregate<<<2500, 256, 0, stream>>>(tmp, row_ptr, csr, h, nullptr, nullptr, 0);
  gemm64<256, true, true, false><<<gmp, 128, 0, stream>>>(h, 256, w2t, mp_b2, deg_inv, tmp, nullptr, 256);
  aggregate<<<2500, 256, 0, stream>>>(tmp, row_ptr, csr, nullptr, A1, A2, 1);
  // FC1 (+inj0 fused, K=512) -> relu -> A2[:, 0:512]
  gemm64<512, true, false, false><<<gfc, 128, 0, stream>>>(A1, 512, wc1t, bias1, nullptr, A2, nullptr, 768);
  // FC2 (+inj1 fused, K=768) -> C2
  gemm64<768, false, false, false><<<gfc, 128, 0, stream>>>(A2, 768, wc2t, bias2, nullptr, C2, nullptr, 512);
  // out = C2 @ out_w + out_b  (fp32 store, row-guarded)
  gemm64<512, false, false, true><<<go, 128, 0, stream>>>(C2, 512, owt, out_b, nullptr, nullptr, out, 64);
}